// Round 12
// baseline (83.529 us; speedup 1.0000x reference)
//
#include <hip/hip_runtime.h>
#include <hip/hip_bf16.h>

#define NEG_SLOPE 0.2f
#define CAP 64

typedef __attribute__((ext_vector_type(8))) short bf16x8;
typedef __attribute__((ext_vector_type(4))) float f32x4;

__device__ __forceinline__ unsigned short f2bf(float f){
  __hip_bfloat16 h = __float2bfloat16(f);
  return *reinterpret_cast<unsigned short*>(&h);
}
__device__ __forceinline__ float bf2f(unsigned short u){
  return __uint_as_float(((unsigned int)u) << 16);
}

// ================= kPre: zero cnt | wvec | W1T/W2T transposes | xbf convert =================
__global__ __launch_bounds__(256) void kPre(int N, const float* __restrict__ x,
    const float* __restrict__ W1, const float* __restrict__ as1v, const float* __restrict__ ad1v,
    const float* __restrict__ W2, const float* __restrict__ as2v, const float* __restrict__ ad2v,
    float* __restrict__ ws1, float* __restrict__ wd1,
    float* __restrict__ ws2, float* __restrict__ wd2,
    unsigned short* __restrict__ W1T, unsigned short* __restrict__ W2T,
    unsigned short* __restrict__ xbf, int* __restrict__ cnt){
  const int t = threadIdx.x, blk = blockIdx.x, G = gridDim.x;
  __shared__ unsigned short tile[64][66];

  for (int i = blk * 256 + t; i < N; i += G * 256) cnt[i] = 0;

  {
    int total = N * 32;
    for (int i = blk * 256 + t; i < total; i += G * 256){
      float4 v = ((const float4*)x)[i];
      unsigned int q0 = (unsigned int)f2bf(v.x) | ((unsigned int)f2bf(v.y) << 16);
      unsigned int q1 = (unsigned int)f2bf(v.z) | ((unsigned int)f2bf(v.w) << 16);
      ((uint2*)xbf)[i] = make_uint2(q0, q1);
    }
  }

  if (blk < 160){
    int b = blk * 4 + (t >> 6);
    int l = t & 63;
    float s = 0.f, d = 0.f;
    if (b < 128){
      #pragma unroll
      for (int j = l; j < 512; j += 64){ float w = W1[b * 512 + j]; s += w * as1v[j]; d += w * ad1v[j]; }
    } else {
      int r = b - 128;
      float w = W2[r * 64 + l];
      s = w * as2v[l]; d = w * ad2v[l];
    }
    #pragma unroll
    for (int o = 32; o > 0; o >>= 1){ s += __shfl_xor(s, o); d += __shfl_xor(d, o); }
    if (l == 0){
      if (b < 128){ ws1[b] = s; wd1[b] = d; }
      else        { ws2[b - 128] = s; wd2[b - 128] = d; }
    }
  } else if (blk < 184){
    int u = blk - 160;
    int rr = t >> 6, cl = t & 63;
    if (u < 16){
      int kt = u >> 3, ct = u & 7;      // W1: 128k x 512c
      #pragma unroll
      for (int r = 0; r < 16; ++r){
        int kr = r * 4 + rr;
        tile[kr][cl] = f2bf(W1[(size_t)(kt * 64 + kr) * 512 + ct * 64 + cl]);
      }
      __syncthreads();
      #pragma unroll
      for (int r = 0; r < 16; ++r){
        int cr = r * 4 + rr;
        W1T[(size_t)(ct * 64 + cr) * 128 + kt * 64 + cl] = tile[cl][cr];
      }
    } else {
      int kt = u - 16;                  // W2: 512k x 64c
      #pragma unroll
      for (int r = 0; r < 16; ++r){
        int kr = r * 4 + rr;
        tile[kr][cl] = f2bf(W2[(size_t)(kt * 64 + kr) * 64 + cl]);
      }
      __syncthreads();
      #pragma unroll
      for (int r = 0; r < 16; ++r){
        int cr = r * 4 + rr;
        W2T[(size_t)cr * 512 + kt * 64 + cl] = tile[cl][cr];
      }
    }
  }
}

// ================= kScat: bucket scatter + alphax (bf16 x reads) =================
__global__ __launch_bounds__(256) void kScat(const int* __restrict__ ei, int E, int N,
                                             int* __restrict__ cnt, int* __restrict__ csr,
                                             const unsigned short* __restrict__ xbf,
                                             const float* __restrict__ ws,
                                             const float* __restrict__ wd,
                                             float* __restrict__ as, float* __restrict__ ad,
                                             int nScat){
  int blk = blockIdx.x;
  if (blk < nScat){
    int i = blk * 256 + threadIdx.x;
    int Etot = E + N;
    if (i >= Etot) return;
    int s, d;
    if (i < E){ s = ei[i]; d = ei[E + i]; } else { s = i - E; d = i - E; }
    int p = atomicAdd(&cnt[d], 1);
    if (p < CAP) csr[(size_t)d * CAP + p] = s;
    return;
  }
  int n = (blk - nScat) * 4 + (threadIdx.x >> 6);
  if (n >= N) return;
  int l = threadIdx.x & 63;
  unsigned int xv = ((const unsigned int*)xbf)[(size_t)n * 64 + l];
  float x0 = bf2f((unsigned short)(xv & 0xffffu));
  float x1 = bf2f((unsigned short)(xv >> 16));
  float2 sv = ((const float2*)ws)[l];
  float2 dv = ((const float2*)wd)[l];
  float s = x0 * sv.x + x1 * sv.y;
  float d = x0 * dv.x + x1 * dv.y;
  #pragma unroll
  for (int o = 32; o > 0; o >>= 1){ s += __shfl_xor(s, o); d += __shfl_xor(d, o); }
  if (l == 0){ as[n] = s; ad[n] = d; }
}

// ================= kAggLayer: fused aggregation-1 (bf16 gather) + MFMA layer =================
#define LROWS 16
__global__ __launch_bounds__(256) void kAggLayer(
    const int* __restrict__ cnt, const int* __restrict__ csr,
    const float* __restrict__ as1, const float* __restrict__ ad1,
    const unsigned short* __restrict__ xbf,
    const unsigned short* __restrict__ W1T, const float* __restrict__ b1,
    const unsigned short* __restrict__ W2T, const float* __restrict__ ws2,
    const float* __restrict__ wd2,
    unsigned short* __restrict__ h2b, float* __restrict__ as2, float* __restrict__ ad2, int N){
  __shared__ __align__(16) unsigned short xs[16 * 136];
  __shared__ __align__(16) unsigned short gs[16 * 520];
  __shared__ float sred[4][16][2];
  int t = threadIdx.x;
  int w = t >> 6, l = t & 63;
  int lg = l >> 4, ln = l & 15;
  int n0 = blockIdx.x * LROWS;

  // ---- aggregation: wave w -> rows [w*4, w*4+4) ----
  int p = l >> 4;      // edge slot 0..3
  int fg = l & 15;     // feature-8 group
  #pragma unroll
  for (int i = 0; i < 4; ++i){
    int row = w * 4 + i;
    int n = n0 + row;
    float accv[8] = {0.f, 0.f, 0.f, 0.f, 0.f, 0.f, 0.f, 0.f};
    if (n < N){
      int deg = min(cnt[n], CAP);
      float adv = ad1[n];
      int sr0 = 0; float v0 = -3.0e38f;
      if (l < deg){
        sr0 = csr[(size_t)n * CAP + l];
        float vv = as1[sr0] + adv;
        v0 = (vv > 0.f) ? vv : NEG_SLOPE * vv;
      }
      float m = v0, ssum = (l < deg) ? 1.f : 0.f;
      #pragma unroll
      for (int o = 32; o > 0; o >>= 1){
        float m2 = __shfl_xor(m, o);
        float s2 = __shfl_xor(ssum, o);
        float mm = fmaxf(m, m2);
        float ns = 0.f;
        if (ssum > 0.f) ns += ssum * __expf(m - mm);
        if (s2  > 0.f) ns += s2  * __expf(m2 - mm);
        m = mm; ssum = ns;
      }
      float inv = 1.0f / ssum;
      float al0 = (l < deg) ? __expf(v0 - m) * inv : 0.f;
      int steps = (deg + 3) >> 2;
      for (int st = 0; st < steps; ++st){
        int e = st * 4 + p;
        float a = __shfl(al0, e);
        int s  = __shfl(sr0, e);
        int4 rv = *(const int4*)(xbf + (size_t)s * 128 + fg * 8);
        const unsigned short* u = (const unsigned short*)&rv;
        #pragma unroll
        for (int j = 0; j < 8; ++j) accv[j] += a * bf2f(u[j]);
      }
      #pragma unroll
      for (int j = 0; j < 8; ++j){
        accv[j] += __shfl_xor(accv[j], 16);
        accv[j] += __shfl_xor(accv[j], 32);
      }
    }
    if (l < 16){
      unsigned int q0 = (unsigned int)f2bf(accv[0]) | ((unsigned int)f2bf(accv[1]) << 16);
      unsigned int q1 = (unsigned int)f2bf(accv[2]) | ((unsigned int)f2bf(accv[3]) << 16);
      unsigned int q2 = (unsigned int)f2bf(accv[4]) | ((unsigned int)f2bf(accv[5]) << 16);
      unsigned int q3 = (unsigned int)f2bf(accv[6]) | ((unsigned int)f2bf(accv[7]) << 16);
      *(int4*)&xs[row * 136 + l * 8] = make_int4(q0, q1, q2, q3);
    }
  }
  __syncthreads();

  // ---- phase A: wave w -> cols [w*128, +128) ----
  int c0 = w * 128;
  bf16x8 af[4];
  #pragma unroll
  for (int kt = 0; kt < 4; ++kt)
    af[kt] = *reinterpret_cast<const bf16x8*>(&xs[ln * 136 + kt * 32 + lg * 8]);

  f32x4 acc[8];
  #pragma unroll
  for (int nt = 0; nt < 8; ++nt) acc[nt] = (f32x4){0.f, 0.f, 0.f, 0.f};
  #pragma unroll
  for (int nt = 0; nt < 8; ++nt){
    const unsigned short* wp = W1T + (size_t)(c0 + nt * 16 + ln) * 128 + lg * 8;
    #pragma unroll
    for (int kt = 0; kt < 4; ++kt){
      bf16x8 bfr = *reinterpret_cast<const bf16x8*>(wp + kt * 32);
      acc[nt] = __builtin_amdgcn_mfma_f32_16x16x32_bf16(af[kt], bfr, acc[nt], 0, 0, 0);
    }
  }

  float ps4[4] = {0, 0, 0, 0}, pd4[4] = {0, 0, 0, 0};
  #pragma unroll
  for (int nt = 0; nt < 8; ++nt){
    int col = c0 + nt * 16 + ln;
    float bb = b1[col], wsv = ws2[col], wdv = wd2[col];
    #pragma unroll
    for (int r = 0; r < 4; ++r){
      float g = fmaxf(acc[nt][r] + bb, 0.f);
      gs[(lg * 4 + r) * 520 + col] = f2bf(g);
      ps4[r] += g * wsv;
      pd4[r] += g * wdv;
    }
  }
  #pragma unroll
  for (int o = 1; o < 16; o <<= 1){
    #pragma unroll
    for (int r = 0; r < 4; ++r){ ps4[r] += __shfl_xor(ps4[r], o); pd4[r] += __shfl_xor(pd4[r], o); }
  }
  if (ln == 0){
    #pragma unroll
    for (int r = 0; r < 4; ++r){ sred[w][lg * 4 + r][0] = ps4[r]; sred[w][lg * 4 + r][1] = pd4[r]; }
  }
  __syncthreads();
  if (t < 32){
    int r = t >> 1, c = t & 1;
    float v = sred[0][r][c] + sred[1][r][c] + sred[2][r][c] + sred[3][r][c];
    int n = n0 + r;
    if (n < N){ if (c == 0) as2[n] = v; else ad2[n] = v; }
  }

  // ---- phase B: wave w -> out-cols [w*16, +16), K = 512; h2 written as bf16 ----
  f32x4 a0 = (f32x4){0.f, 0.f, 0.f, 0.f}, a1 = (f32x4){0.f, 0.f, 0.f, 0.f};
  const unsigned short* wp2 = W2T + (size_t)(w * 16 + ln) * 512 + lg * 8;
  #pragma unroll
  for (int kt = 0; kt < 16; kt += 2){
    bf16x8 afa = *reinterpret_cast<const bf16x8*>(&gs[ln * 520 + kt * 32 + lg * 8]);
    bf16x8 bfa = *reinterpret_cast<const bf16x8*>(wp2 + kt * 32);
    a0 = __builtin_amdgcn_mfma_f32_16x16x32_bf16(afa, bfa, a0, 0, 0, 0);
    bf16x8 afb = *reinterpret_cast<const bf16x8*>(&gs[ln * 520 + (kt + 1) * 32 + lg * 8]);
    bf16x8 bfb = *reinterpret_cast<const bf16x8*>(wp2 + (kt + 1) * 32);
    a1 = __builtin_amdgcn_mfma_f32_16x16x32_bf16(afb, bfb, a1, 0, 0, 0);
  }
  #pragma unroll
  for (int r = 0; r < 4; ++r){
    int n = n0 + lg * 4 + r;
    if (n < N) h2b[(size_t)n * 64 + w * 16 + ln] = f2bf(a0[r] + a1[r]);
  }
}

// ================= aggregation-2 (deg <= 64), bf16 gather of h2 =================
__global__ __launch_bounds__(256) void kAgg2(const int* __restrict__ cnt, const int* __restrict__ csr,
    const float* __restrict__ as, const float* __restrict__ ad,
    const unsigned short* __restrict__ h2b,
    const float* __restrict__ bias, float* __restrict__ out, int N){
  int n = blockIdx.x * 4 + (threadIdx.x >> 6);
  if (n >= N) return;
  int l = threadIdx.x & 63;
  int deg = min(cnt[n], CAP);
  float adv = ad[n];
  int sr0 = 0; float v0 = -3.0e38f;
  if (l < deg){
    sr0 = csr[(size_t)n * CAP + l];
    float vv = as[sr0] + adv;
    v0 = (vv > 0.f) ? vv : NEG_SLOPE * vv;
  }
  float m = v0, ssum = (l < deg) ? 1.f : 0.f;
  #pragma unroll
  for (int o = 32; o > 0; o >>= 1){
    float m2 = __shfl_xor(m, o);
    float s2 = __shfl_xor(ssum, o);
    float mm = fmaxf(m, m2);
    float ns = 0.f;
    if (ssum > 0.f) ns += ssum * __expf(m - mm);
    if (s2  > 0.f) ns += s2  * __expf(m2 - mm);
    m = mm; ssum = ns;
  }
  float inv = 1.0f / ssum;
  float al0 = (l < deg) ? __expf(v0 - m) * inv : 0.f;

  int p = l >> 3;      // 8 edge slots
  int fg = l & 7;      // 8-feature group (8 bf16 = 16B per lane)
  float accv[8] = {0.f, 0.f, 0.f, 0.f, 0.f, 0.f, 0.f, 0.f};
  int steps = (deg + 7) >> 3;
  #pragma unroll 4
  for (int i = 0; i < steps; ++i){
    int e = i * 8 + p;
    float a = __shfl(al0, e);
    int s  = __shfl(sr0, e);
    int4 rv = *(const int4*)(h2b + (size_t)s * 64 + fg * 8);
    const unsigned short* u = (const unsigned short*)&rv;
    #pragma unroll
    for (int j = 0; j < 8; ++j) accv[j] += a * bf2f(u[j]);
  }
  #pragma unroll
  for (int j = 0; j < 8; ++j){
    accv[j] += __shfl_xor(accv[j], 8);
    accv[j] += __shfl_xor(accv[j], 16);
    accv[j] += __shfl_xor(accv[j], 32);
  }
  if (l < 8){
    float4 bv0 = ((const float4*)bias)[l * 2];
    float4 bv1 = ((const float4*)bias)[l * 2 + 1];
    float4 o0 = make_float4(fmaxf(accv[0] + bv0.x, 0.f), fmaxf(accv[1] + bv0.y, 0.f),
                            fmaxf(accv[2] + bv0.z, 0.f), fmaxf(accv[3] + bv0.w, 0.f));
    float4 o1 = make_float4(fmaxf(accv[4] + bv1.x, 0.f), fmaxf(accv[5] + bv1.y, 0.f),
                            fmaxf(accv[6] + bv1.z, 0.f), fmaxf(accv[7] + bv1.w, 0.f));
    ((float4*)(out + (size_t)n * 64 + l * 8))[0] = o0;
    ((float4*)(out + (size_t)n * 64 + l * 8))[1] = o1;
  }
}

// ================= mean pool + FC fused =================
__device__ __forceinline__ int lbound(const int* a, int n, int v){
  int lo = 0, hi = n;
  while (lo < hi){ int mid = (lo + hi) >> 1; if (a[mid] < v) lo = mid + 1; else hi = mid; }
  return lo;
}

__global__ __launch_bounds__(256) void k_poolfc(const float* __restrict__ g2, const int* __restrict__ batch,
                                                const float* __restrict__ fcW, const float* __restrict__ fcb,
                                                float* __restrict__ out, int N){
  int g = blockIdx.x;
  __shared__ int sb[2];
  if (threadIdx.x == 0){ sb[0] = lbound(batch, N, g); sb[1] = lbound(batch, N, g + 1); }
  __syncthreads();
  int r0 = sb[0], r1 = sb[1];
  int f = threadIdx.x & 63, ch = threadIdx.x >> 6;
  float s = 0.f;
  for (int r = r0 + ch; r < r1; r += 4) s += g2[(size_t)r * 64 + f];
  __shared__ float red[4][64];
  red[ch][f] = s;
  __syncthreads();
  if (ch == 0){
    float tot = red[0][f] + red[1][f] + red[2][f] + red[3][f];
    float c = fmaxf((float)(r1 - r0), 1.f);
    float p = tot / c;
    float o0 = p * fcW[f * 2 + 0];
    float o1 = p * fcW[f * 2 + 1];
    #pragma unroll
    for (int o = 32; o > 0; o >>= 1){ o0 += __shfl_xor(o0, o); o1 += __shfl_xor(o1, o); }
    if (f == 0){ out[g * 2 + 0] = o0 + fcb[0]; out[g * 2 + 1] = o1 + fcb[1]; }
  }
}

extern "C" void kernel_launch(void* const* d_in, const int* in_sizes, int n_in,
                              void* d_out, int out_size, void* d_ws, size_t ws_size,
                              hipStream_t stream){
  const float* x    = (const float*)d_in[0];
  const int* ei     = (const int*)d_in[1];
  const int* batch  = (const int*)d_in[2];
  const float* W1   = (const float*)d_in[3];
  const float* as1w = (const float*)d_in[4];
  const float* ad1w = (const float*)d_in[5];
  const float* b1   = (const float*)d_in[6];
  const float* W2   = (const float*)d_in[7];
  const float* as2w = (const float*)d_in[8];
  const float* ad2w = (const float*)d_in[9];
  const float* b2   = (const float*)d_in[10];
  const float* fcW  = (const float*)d_in[11];
  const float* fcb  = (const float*)d_in[12];
  float* out = (float*)d_out;

  const int N    = in_sizes[2];
  const int E    = in_sizes[1] / 2;
  const int NG   = out_size / 2;
  const int Etot = E + N;

  char* base = (char*)d_ws;
  size_t o = 0;
  auto take = [&](size_t bytes) -> char* {
    char* r = base + o;
    o = (o + bytes + 255) & ~(size_t)255;
    return r;
  };
  unsigned short* xbf = (unsigned short*)take((size_t)(N + 16) * 128 * 2);
  unsigned short* h2b = (unsigned short*)take((size_t)(N + 16) * 64 * 2);
  float* g2   = (float*)take((size_t)(N + 16) * 64 * 4);
  float* as1  = (float*)take((size_t)N * 4);
  float* ad1  = (float*)take((size_t)N * 4);
  float* as2  = (float*)take((size_t)N * 4);
  float* ad2  = (float*)take((size_t)N * 4);
  float* ws1  = (float*)take(128 * 4);
  float* wd1  = (float*)take(128 * 4);
  float* ws2  = (float*)take(512 * 4);
  float* wd2  = (float*)take(512 * 4);
  unsigned short* W1T = (unsigned short*)take((size_t)128 * 512 * 2);
  unsigned short* W2T = (unsigned short*)take((size_t)512 * 64 * 2);
  int*   cnt  = (int*)take((size_t)N * 4);
  int*   csr  = (int*)take((size_t)N * CAP * 4);

  kPre<<<184, 256, 0, stream>>>(N, x, W1, as1w, ad1w, W2, as2w, ad2w,
                                ws1, wd1, ws2, wd2, W1T, W2T, xbf, cnt);

  const int nScat = (Etot + 255) / 256;
  kScat<<<nScat + (N + 3) / 4, 256, 0, stream>>>(ei, E, N, cnt, csr, xbf, ws1, wd1, as1, ad1, nScat);

  kAggLayer<<<(N + LROWS - 1) / LROWS, 256, 0, stream>>>(cnt, csr, as1, ad1, xbf,
                                                         W1T, b1, W2T, ws2, wd2, h2b, as2, ad2, N);
  kAgg2<<<(N + 3) / 4, 256, 0, stream>>>(cnt, csr, as2, ad2, h2b, b2, g2, N);

  k_poolfc<<<NG, 256, 0, stream>>>(g2, batch, fcW, fcb, out, N);
}